// Round 8
// baseline (164.957 us; speedup 1.0000x reference)
//
#include <hip/hip_runtime.h>
#include <hip/hip_bf16.h>

// Problem constants
constexpr int B      = 16384;
constexpr int D_IN   = 1024;
constexpr int D_OUT  = 256;
constexpr int NCLS   = 1000;
constexpr int CPAD   = 1024;   // padded class count

// ---------------- workspace layout (byte offsets) ----------------
constexpr size_t OFF_XB   = 0;                                    // B*D_IN bf16   (32 MB)
constexpr size_t OFF_WB   = OFF_XB  + (size_t)B * D_IN * 2;       // 512*D_IN bf16 (1 MB)
constexpr size_t OFF_S    = OFF_WB  + (size_t)512 * D_IN * 2;     // CPAD*D_IN f32 (4 MB)
constexpr size_t OFF_Z    = OFF_S   + (size_t)CPAD * D_IN * 4;    // CPAD*D_OUT f32 (1 MB, zeroed)
constexpr size_t OFF_T    = OFF_Z   + (size_t)CPAD * D_OUT * 4;   // D_IN f32 (zeroed)
constexpr size_t OFF_CNT  = OFF_T   + (size_t)D_IN * 4;           // CPAD int (written by segsum)

typedef short bf16x8 __attribute__((ext_vector_type(8)));
typedef float f32x4  __attribute__((ext_vector_type(4)));

// fp32 -> bf16 round-to-nearest-even
__device__ __forceinline__ unsigned short f2bf(float f) {
    unsigned int u = __float_as_uint(f);
    return (unsigned short)((u + 0x7FFFu + ((u >> 16) & 1u)) >> 16);
}

__device__ __forceinline__ void cvt8(const float4& a, const float4& b, unsigned short* dst) {
    union { unsigned short u[8]; bf16x8 v; } r;
    r.u[0] = f2bf(a.x); r.u[1] = f2bf(a.y); r.u[2] = f2bf(a.z); r.u[3] = f2bf(a.w);
    r.u[4] = f2bf(b.x); r.u[5] = f2bf(b.y); r.u[6] = f2bf(b.z); r.u[7] = f2bf(b.w);
    *(bf16x8*)dst = r.v;
}

__device__ __forceinline__ ushort4 f2bf4(const float4& a) {
    ushort4 r;
    r.x = f2bf(a.x); r.y = f2bf(a.y); r.z = f2bf(a.z); r.w = f2bf(a.w);
    return r;
}

// async global->LDS, 16B/lane; lds dst = wave-uniform base (+lane*16 implied by HW)
__device__ __forceinline__ void async16(const unsigned short* g, unsigned short* l) {
    __builtin_amdgcn_global_load_lds(
        (const __attribute__((address_space(1))) void*)g,
        (__attribute__((address_space(3))) void*)l,
        16, 0, 0);
}

// ---- 1. convert W1,W2 -> Wb bf16; zero T, Z (256 blocks) ----
__global__ void cvtw_zero_kernel(const float* __restrict__ W1, const float* __restrict__ W2,
                                 unsigned short* __restrict__ Wb,
                                 float* __restrict__ T, float* __restrict__ Z) {
    int lin = blockIdx.x * blockDim.x + threadIdx.x;   // 0..65535
    int i = lin * 8;
    const float* src = (i < D_OUT * D_IN) ? (W1 + i) : (W2 + (i - D_OUT * D_IN));
    float4 a = *(const float4*)(src);
    float4 b = *(const float4*)(src + 4);
    cvt8(a, b, Wb + i);
    if (lin < D_IN) T[lin] = 0.f;
    *(float4*)(Z + (size_t)lin * 4) = float4{0.f, 0.f, 0.f, 0.f};   // 65536*4 floats
}

// ---- 2. per-class sums of x + cnt + xb emit; finds rows by scanning labels ----
__global__ __launch_bounds__(256)
void segsum_kernel(const float* __restrict__ x,
                   const int* __restrict__ label,
                   int* __restrict__ cnt,
                   float* __restrict__ s,
                   unsigned short* __restrict__ xb) {
    __shared__ int rows[512];     // class size ~Binom(16384,1e-3): mean 16, 512 = safe
    __shared__ int nrows;
    const int c = blockIdx.x;     // 0..1023
    const int t = threadIdx.x;
    if (t == 0) nrows = 0;
    __syncthreads();
    // find this class's rows (label array is L2/L3-hot, 64 KB)
    for (int i = t; i < B; i += 256)
        if (label[i] == c) {
            int p = atomicAdd(&nrows, 1);
            rows[p] = i;
        }
    __syncthreads();
    const int n = nrows;
    if (t == 0) cnt[c] = n;

    const int col = t * 4;
    float4 acc = {0.f, 0.f, 0.f, 0.f};
    int r = 0;
    for (; r + 4 <= n; r += 4) {
        int i0 = rows[r + 0];
        int i1 = rows[r + 1];
        int i2 = rows[r + 2];
        int i3 = rows[r + 3];
        float4 v0 = *(const float4*)(x + (size_t)i0 * D_IN + col);
        float4 v1 = *(const float4*)(x + (size_t)i1 * D_IN + col);
        float4 v2 = *(const float4*)(x + (size_t)i2 * D_IN + col);
        float4 v3 = *(const float4*)(x + (size_t)i3 * D_IN + col);
        *(ushort4*)(xb + (size_t)i0 * D_IN + col) = f2bf4(v0);
        *(ushort4*)(xb + (size_t)i1 * D_IN + col) = f2bf4(v1);
        *(ushort4*)(xb + (size_t)i2 * D_IN + col) = f2bf4(v2);
        *(ushort4*)(xb + (size_t)i3 * D_IN + col) = f2bf4(v3);
        acc.x += (v0.x + v1.x) + (v2.x + v3.x);
        acc.y += (v0.y + v1.y) + (v2.y + v3.y);
        acc.z += (v0.z + v1.z) + (v2.z + v3.z);
        acc.w += (v0.w + v1.w) + (v2.w + v3.w);
    }
    for (; r < n; ++r) {
        int i0 = rows[r];
        float4 v = *(const float4*)(x + (size_t)i0 * D_IN + col);
        *(ushort4*)(xb + (size_t)i0 * D_IN + col) = f2bf4(v);
        acc.x += v.x; acc.y += v.y; acc.z += v.z; acc.w += v.w;
    }
    *(float4*)(s + (size_t)c * D_IN + col) = acc;
}

// ---- 3. T = column-sum of s (64 blocks, 64 atomics/address) ----
__global__ void tsum_kernel(const float* __restrict__ s, float* __restrict__ T) {
    int col = threadIdx.x * 4;
    int c0 = blockIdx.x * 16;
    float4 acc = {0.f, 0.f, 0.f, 0.f};
#pragma unroll 4
    for (int c = 0; c < 16; ++c) {
        float4 v = *(const float4*)(s + (size_t)(c0 + c) * D_IN + col);
        acc.x += v.x; acc.y += v.y; acc.z += v.z; acc.w += v.w;
    }
    atomicAdd(&T[col + 0], acc.x);
    atomicAdd(&T[col + 1], acc.y);
    atomicAdd(&T[col + 2], acc.z);
    atomicAdd(&T[col + 3], acc.w);
}

// ---- 4. Z[c] += ((T - s_c)/d_c) @ W2^T (+ b2 in chunk 0); 64x64 tile, BK=64, K-split x4
__global__ __launch_bounds__(256)
void meanz_kernel(const float* __restrict__ s,
                  const float* __restrict__ T,
                  const int* __restrict__ cnt,
                  const unsigned short* __restrict__ Wb,
                  const float* __restrict__ b2,
                  float* __restrict__ Z) {
    __shared__ unsigned short As[4096];   // two 64x32 panels
    __shared__ unsigned short Bs[4096];

    const int tid  = threadIdx.x;
    const int wave = tid >> 6;
    const int lane = tid & 63;
    const int quad = lane >> 4;
    const int l16  = lane & 15;
    const int bm   = blockIdx.x * 64;   // class base
    const int bn   = blockIdx.y * 64;   // out-col base
    const int kb   = blockIdx.z * 256;  // K chunk
    const int wm   = (wave >> 1) * 32;
    const int wn   = (wave & 1) * 32;

    const int arow = tid >> 2;          // 0..63
    const int akc  = (tid & 3) * 8;     // 0,8,16,24

    const int cls = bm + arow;
    const int d   = B - cnt[cls];       // cnt[c]=0 for pad classes
    const float scale = (d > 0) ? 1.f / (float)d : 0.f;
    const float* sp = s + (size_t)cls * D_IN + akc;
    const float* tp = T + akc;

    // B async chunk mapping: per panel 1 chunk of 16B per thread
    const int bidx = wave * 64 + lane;
    const int brow = bidx >> 2;
    const int bkc  = (bidx & 3) * 8;
    const unsigned short* bp = Wb + (size_t)(256 + bn + brow) * D_IN + bkc;

    f32x4 acc[2][2] = {};

    for (int k0 = kb; k0 < kb + 256; k0 += 64) {
        float4 s0 = *(const float4*)(sp + k0);
        float4 s1 = *(const float4*)(sp + k0 + 4);
        float4 s2 = *(const float4*)(sp + k0 + 32);
        float4 s3 = *(const float4*)(sp + k0 + 36);
        float4 t0 = *(const float4*)(tp + k0);
        float4 t1 = *(const float4*)(tp + k0 + 4);
        float4 t2 = *(const float4*)(tp + k0 + 32);
        float4 t3 = *(const float4*)(tp + k0 + 36);
        __syncthreads();   // previous iteration's frag reads complete
        async16(bp + k0,      Bs + wave * 512);
        async16(bp + k0 + 32, Bs + 2048 + wave * 512);
        float4 m0 = {(t0.x - s0.x) * scale, (t0.y - s0.y) * scale,
                     (t0.z - s0.z) * scale, (t0.w - s0.w) * scale};
        float4 m1 = {(t1.x - s1.x) * scale, (t1.y - s1.y) * scale,
                     (t1.z - s1.z) * scale, (t1.w - s1.w) * scale};
        float4 m2 = {(t2.x - s2.x) * scale, (t2.y - s2.y) * scale,
                     (t2.z - s2.z) * scale, (t2.w - s2.w) * scale};
        float4 m3 = {(t3.x - s3.x) * scale, (t3.y - s3.y) * scale,
                     (t3.z - s3.z) * scale, (t3.w - s3.w) * scale};
        cvt8(m0, m1, As + arow * 32 + akc);
        cvt8(m2, m3, As + 2048 + arow * 32 + akc);
        __syncthreads();   // drains vmcnt (async B) + lgkm (A writes)

#pragma unroll
        for (int p = 0; p < 2; ++p) {
            bf16x8 af[2], bfr[2];
#pragma unroll
            for (int t = 0; t < 2; ++t) {
                af[t]  = *(const bf16x8*)&As[p * 2048 + (wm + t * 16 + l16) * 32 + quad * 8];
                bfr[t] = *(const bf16x8*)&Bs[p * 2048 + (wn + t * 16 + l16) * 32 + quad * 8];
            }
#pragma unroll
            for (int i = 0; i < 2; ++i)
#pragma unroll
                for (int j = 0; j < 2; ++j)
                    acc[i][j] = __builtin_amdgcn_mfma_f32_16x16x32_bf16(af[i], bfr[j], acc[i][j], 0, 0, 0);
        }
    }

    const bool addb = (blockIdx.z == 0);
#pragma unroll
    for (int j = 0; j < 2; ++j) {
        const int n = bn + wn + j * 16 + l16;
        const float bias = addb ? b2[n] : 0.f;
#pragma unroll
        for (int i = 0; i < 2; ++i)
#pragma unroll
            for (int r = 0; r < 4; ++r) {
                const int c = bm + wm + i * 16 + quad * 4 + r;
                atomicAdd(&Z[(size_t)c * D_OUT + n], acc[i][j][r] + bias);
            }
    }
}

// ---- 5. out = xb @ W1b^T + b1 + Z[label] ; 64x64 tile, BK=64, all-async staging ----
__global__ __launch_bounds__(256)
void gemm1_kernel(const unsigned short* __restrict__ xb,
                  const unsigned short* __restrict__ Wb,
                  const float* __restrict__ b1,
                  const float* __restrict__ Z,
                  const int* __restrict__ label,
                  float* __restrict__ out) {
    __shared__ unsigned short As[4096];   // two 64x32 panels
    __shared__ unsigned short Bs[4096];

    const int tid  = threadIdx.x;
    const int wave = tid >> 6;
    const int lane = tid & 63;
    const int quad = lane >> 4;
    const int l16  = lane & 15;
    const int bm   = blockIdx.x * 64;
    const int bn   = blockIdx.y * 64;
    const int wm   = (wave >> 1) * 32;
    const int wn   = (wave & 1) * 32;

    // async chunk mapping: per panel 1 chunk of 16B per thread per matrix
    const int idx = wave * 64 + lane;
    const int row = idx >> 2;
    const int kc  = (idx & 3) * 8;
    const unsigned short* ap = xb + (size_t)(bm + row) * D_IN + kc;
    const unsigned short* bp = Wb + (size_t)(bn + row) * D_IN + kc;

    // epilogue prefetch: label rows, Z gather, bias — latency hides under K-loop
    int zrow[2][4];
#pragma unroll
    for (int i = 0; i < 2; ++i)
#pragma unroll
        for (int r = 0; r < 4; ++r)
            zrow[i][r] = label[bm + wm + i * 16 + quad * 4 + r] * D_OUT;
    float bb[2];
    float zv[2][2][4];
#pragma unroll
    for (int j = 0; j < 2; ++j) {
        const int n = bn + wn + j * 16 + l16;
        bb[j] = b1[n];
#pragma unroll
        for (int i = 0; i < 2; ++i)
#pragma unroll
            for (int r = 0; r < 4; ++r)
                zv[j][i][r] = Z[zrow[i][r] + n];
    }

    f32x4 acc[2][2] = {};

    for (int k0 = 0; k0 < D_IN; k0 += 64) {
        __syncthreads();   // previous iteration's frag reads complete
        async16(ap + k0,      As + wave * 512);
        async16(ap + k0 + 32, As + 2048 + wave * 512);
        async16(bp + k0,      Bs + wave * 512);
        async16(bp + k0 + 32, Bs + 2048 + wave * 512);
        __syncthreads();   // vmcnt drain before frag reads

#pragma unroll
        for (int p = 0; p < 2; ++p) {
            bf16x8 af[2], bfr[2];
#pragma unroll
            for (int t = 0; t < 2; ++t) {
                af[t]  = *(const bf16x8*)&As[p * 2048 + (wm + t * 16 + l16) * 32 + quad * 8];
                bfr[t] = *(const bf16x8*)&Bs[p * 2048 + (wn + t * 16 + l16) * 32 + quad * 8];
            }
#pragma unroll
            for (int i = 0; i < 2; ++i)
#pragma unroll
                for (int j = 0; j < 2; ++j)
                    acc[i][j] = __builtin_amdgcn_mfma_f32_16x16x32_bf16(af[i], bfr[j], acc[i][j], 0, 0, 0);
        }
    }

    // epilogue: out[m][n] = acc + b1[n] + Z[label[m]][n]
#pragma unroll
    for (int j = 0; j < 2; ++j) {
        const int n = bn + wn + j * 16 + l16;
#pragma unroll
        for (int i = 0; i < 2; ++i)
#pragma unroll
            for (int r = 0; r < 4; ++r) {
                const int m = bm + wm + i * 16 + quad * 4 + r;
                out[(size_t)m * D_OUT + n] = acc[i][j][r] + bb[j] + zv[j][i][r];
            }
    }
}

// ---------------- launcher ----------------
extern "C" void kernel_launch(void* const* d_in, const int* in_sizes, int n_in,
                              void* d_out, int out_size, void* d_ws, size_t ws_size,
                              hipStream_t stream) {
    const float* x    = (const float*)d_in[0];
    const int*   lab  = (const int*)d_in[1];
    const float* W1_w = (const float*)d_in[2];
    const float* W1_b = (const float*)d_in[3];
    const float* W2_w = (const float*)d_in[4];
    const float* W2_b = (const float*)d_in[5];
    float* out = (float*)d_out;

    char* ws = (char*)d_ws;
    unsigned short* xb = (unsigned short*)(ws + OFF_XB);
    unsigned short* Wb = (unsigned short*)(ws + OFF_WB);
    float* s   = (float*)(ws + OFF_S);
    float* Z   = (float*)(ws + OFF_Z);
    float* T   = (float*)(ws + OFF_T);
    int* cnt   = (int*)(ws + OFF_CNT);

    // 1. Wb convert + zero T/Z
    cvtw_zero_kernel<<<256, 256, 0, stream>>>(W1_w, W2_w, Wb, T, Z);
    // 2. per-class sums + cnt + xb emit (self-contained label scan)
    segsum_kernel<<<CPAD, 256, 0, stream>>>(x, lab, cnt, s, xb);
    // 3. grand total
    tsum_kernel<<<64, 256, 0, stream>>>(s, T);
    // 4. Z table (BK=64, K-split x4)
    dim3 zgrid(CPAD / 64, D_OUT / 64, 4);
    meanz_kernel<<<zgrid, 256, 0, stream>>>(s, T, cnt, Wb, W2_b, Z);
    // 5. main GEMM (BK=64, pure-bf16 async staging, prefetched epilogue)
    dim3 ggrid(B / 64, D_OUT / 64);
    gemm1_kernel<<<ggrid, 256, 0, stream>>>(xb, Wb, W1_b, Z, lab, out);
}